// Round 3
// baseline (33.180 us; speedup 1.0000x reference)
//
#include <hip/hip_runtime.h>
#include <math.h>

#define NPART 1024
#define BLOCK 256

// Block-level sum reduction for BLOCK=256 (4 waves of 64).
__device__ __forceinline__ float block_reduce_sum(float v) {
    __shared__ float smem[BLOCK / 64];
    const int lane = threadIdx.x & 63;
    const int wave = threadIdx.x >> 6;
    #pragma unroll
    for (int off = 32; off > 0; off >>= 1)
        v += __shfl_down(v, off, 64);
    if (lane == 0) smem[wave] = v;
    __syncthreads();
    if (wave == 0) {
        v = (lane < (BLOCK / 64)) ? smem[lane] : 0.0f;
        v += __shfl_down(v, 2, 64);
        v += __shfl_down(v, 1, 64);
    }
    return v;  // valid in threadIdx.x == 0
}

// Per-element: S = log( exp(-S0/2) * M * exp(-S0/2) ); return ||S||_F^2.
__device__ __forceinline__ float metric_elem(float p0, float p1, float p2,
                                             float m00, float m01, float m11) {
    // ---- T = exp(A), A = -S0/2 ----
    const float am = -0.25f * (p0 + p2);
    const float ad = -0.25f * (p0 - p2);
    const float ab = -0.5f  * p1;
    const float ar = sqrtf(ad * ad + ab * ab);
    const float e1 = __expf(am + ar);
    const float e2 = __expf(am - ar);
    const float ec0 = 0.5f * (e1 + e2);
    const float ec1 = 0.5f * (e1 - e2) / fmaxf(ar, 1e-20f);
    const float t00 = ec0 + ec1 * ad;
    const float t01 = ec1 * ab;
    const float t11 = ec0 - ec1 * ad;

    // ---- R = T * M * T ----
    const float x00 = t00 * m00 + t01 * m01;
    const float x01 = t00 * m01 + t01 * m11;
    const float x10 = t01 * m00 + t11 * m01;
    const float x11 = t01 * m01 + t11 * m11;
    const float r00 = x00 * t00 + x01 * t01;
    const float r01 = x00 * t01 + x01 * t11;
    const float r10 = x10 * t00 + x11 * t01;
    const float r11 = x10 * t01 + x11 * t11;
    const float rb  = 0.5f * (r01 + r10);

    // ---- S = log(R) ----
    const float lm = 0.5f * (r00 + r11);
    const float ld = 0.5f * (r00 - r11);
    const float lr = sqrtf(ld * ld + rb * rb);
    const float lam1 = lm + lr;
    const float lam2 = fmaxf(lm - lr, 1e-30f);
    const float g1 = __logf(lam1);
    const float g2 = __logf(lam2);
    const float lc0 = 0.5f * (g1 + g2);
    const float lc1 = 0.5f * (g1 - g2) / fmaxf(lr, 1e-20f);
    const float s00 = lc0 + lc1 * ld;
    const float s01 = lc1 * rb;
    const float s11 = lc0 - lc1 * ld;

    return s00 * s00 + s11 * s11 + 2.0f * s01 * s01;
}

// Single fused kernel: grid-stride compute + partials, then the LAST block
// (device-scope ticket) deterministically reduces all partials.
__global__ __launch_bounds__(BLOCK) void metric_fused_kernel(
        const float* __restrict__ pred, const float* __restrict__ act,
        float* __restrict__ partial, unsigned int* __restrict__ counter,
        float* __restrict__ out, int B, float inv_b) {
    const int tid = blockIdx.x * BLOCK + threadIdx.x;
    const int stride = gridDim.x * BLOCK;
    const int G = B >> 2;                   // full groups of 4 elements
    const float4* __restrict__ p4 = (const float4*)pred;
    const float4* __restrict__ a4 = (const float4*)act;

    float acc = 0.0f;
    for (int g = tid; g < G; g += stride) {
        const float4 pa = p4[3 * g + 0];
        const float4 pb = p4[3 * g + 1];
        const float4 pc = p4[3 * g + 2];
        const float4 qa = a4[3 * g + 0];
        const float4 qb = a4[3 * g + 1];
        const float4 qc = a4[3 * g + 2];
        acc += metric_elem(pa.x, pa.y, pa.z, qa.x, qa.y, qa.z);
        acc += metric_elem(pa.w, pb.x, pb.y, qa.w, qb.x, qb.y);
        acc += metric_elem(pb.z, pb.w, pc.x, qb.z, qb.w, qc.x);
        acc += metric_elem(pc.y, pc.z, pc.w, qc.y, qc.z, qc.w);
    }
    // tail (B % 4 elements), scalar path
    const int tail_start = G << 2;
    for (int i = tail_start + tid; i < B; i += stride) {
        acc += metric_elem(pred[3 * i], pred[3 * i + 1], pred[3 * i + 2],
                           act[3 * i], act[3 * i + 1], act[3 * i + 2]);
    }

    const float bsum = block_reduce_sum(acc);

    __shared__ int sIsLast;
    if (threadIdx.x == 0) {
        partial[blockIdx.x] = bsum;
        __threadfence();                       // publish partial before ticket
        const unsigned int ticket = atomicAdd(counter, 1u);
        sIsLast = (ticket == gridDim.x - 1);
    }
    __syncthreads();

    if (sIsLast) {
        __threadfence();                       // acquire all published partials
        // NPART/BLOCK = 4 partials per thread, fixed order -> deterministic.
        float a = partial[threadIdx.x]
                + partial[threadIdx.x + 256]
                + partial[threadIdx.x + 512]
                + partial[threadIdx.x + 768];
        const float total = block_reduce_sum(a);
        if (threadIdx.x == 0) out[0] = total * inv_b;
    }
}

extern "C" void kernel_launch(void* const* d_in, const int* in_sizes, int n_in,
                              void* d_out, int out_size, void* d_ws, size_t ws_size,
                              hipStream_t stream) {
    const float* pred = (const float*)d_in[0];
    const float* act  = (const float*)d_in[1];
    float* out = (float*)d_out;
    float* partial = (float*)d_ws;                              // NPART floats
    unsigned int* counter = (unsigned int*)((char*)d_ws + NPART * sizeof(float));

    const int B = in_sizes[0] / 3;

    hipMemsetAsync(counter, 0, sizeof(unsigned int), stream);   // zero ticket
    metric_fused_kernel<<<NPART, BLOCK, 0, stream>>>(
        pred, act, partial, counter, out, B, 1.0f / (float)B);
}

// Round 4
// 12.377 us; speedup vs baseline: 2.6809x; 2.6809x over previous
//
#include <hip/hip_runtime.h>
#include <math.h>

#define NPART 1024
#define BLOCK 256

// Block-level sum reduction for BLOCK=256 (4 waves of 64).
__device__ __forceinline__ float block_reduce_sum(float v) {
    __shared__ float smem[BLOCK / 64];
    const int lane = threadIdx.x & 63;
    const int wave = threadIdx.x >> 6;
    #pragma unroll
    for (int off = 32; off > 0; off >>= 1)
        v += __shfl_down(v, off, 64);
    if (lane == 0) smem[wave] = v;
    __syncthreads();
    if (wave == 0) {
        v = (lane < (BLOCK / 64)) ? smem[lane] : 0.0f;
        v += __shfl_down(v, 2, 64);
        v += __shfl_down(v, 1, 64);
    }
    return v;  // valid in threadIdx.x == 0
}

// ||log(T M T)||_F^2 with T = exp(-S0/2), via eigenvalues only:
//   R = T M T (symmetric, SPD)  =>  ||log R||_F^2 = log^2(mu1) + log^2(mu2)
//   tr(R)  = tr(M * E),  E = exp(-S0)   (cyclic trace, T^2 = E)
//   det(R) = det(E) * det(M) = e1*e2 * det(M)
//   log(mu2) = log(det R) - log(mu1)
__device__ __forceinline__ float metric_elem(float p0, float p1, float p2,
                                             float m00, float m01, float m11) {
    // ---- E = exp(-S0), closed form for symmetric 2x2 ----
    const float am = -0.5f * (p0 + p2);
    const float ad = -0.5f * (p0 - p2);
    const float ab = -p1;
    const float r  = sqrtf(ad * ad + ab * ab);
    const float e1 = __expf(am + r);
    const float e2 = __expf(am - r);
    const float c0 = 0.5f * (e1 + e2);
    const float c1 = 0.5f * (e1 - e2) / fmaxf(r, 1e-20f);

    // ---- tr(R) = c0*(m00+m11) + c1*(ad*(m00-m11) + 2*ab*m01) ----
    const float trR  = c0 * (m00 + m11) + c1 * (ad * (m00 - m11) + 2.0f * ab * m01);
    // ---- det(R) = e1*e2 * (m00*m11 - m01^2)  (SPD => > 0) ----
    const float detR = (e1 * e2) * (m00 * m11 - m01 * m01);

    // ---- eigenvalues of R ----
    const float h  = 0.5f * trR;
    const float q  = sqrtf(fmaxf(h * h - detR, 0.0f));
    const float mu1 = h + q;                       // >= mu2 > 0

    const float g1 = __logf(mu1);
    const float g2 = __logf(detR) - g1;            // log(mu2)
    return g1 * g1 + g2 * g2;
}

// Each "group" = 4 elements = 12 floats = 3 float4 per input array.
__global__ __launch_bounds__(BLOCK) void metric_partial_kernel(
        const float* __restrict__ pred, const float* __restrict__ act,
        float* __restrict__ partial, int B) {
    const int tid = blockIdx.x * BLOCK + threadIdx.x;
    const int stride = gridDim.x * BLOCK;
    const int G = B >> 2;                   // full groups of 4
    const float4* __restrict__ p4 = (const float4*)pred;
    const float4* __restrict__ a4 = (const float4*)act;

    float acc = 0.0f;
    for (int g = tid; g < G; g += stride) {
        const float4 pa = p4[3 * g + 0];
        const float4 pb = p4[3 * g + 1];
        const float4 pc = p4[3 * g + 2];
        const float4 qa = a4[3 * g + 0];
        const float4 qb = a4[3 * g + 1];
        const float4 qc = a4[3 * g + 2];
        acc += metric_elem(pa.x, pa.y, pa.z, qa.x, qa.y, qa.z);
        acc += metric_elem(pa.w, pb.x, pb.y, qa.w, qb.x, qb.y);
        acc += metric_elem(pb.z, pb.w, pc.x, qb.z, qb.w, qc.x);
        acc += metric_elem(pc.y, pc.z, pc.w, qc.y, qc.z, qc.w);
    }
    // tail (B % 4 elements), scalar path
    const int tail_start = G << 2;
    for (int i = tail_start + tid; i < B; i += stride) {
        acc += metric_elem(pred[3 * i], pred[3 * i + 1], pred[3 * i + 2],
                           act[3 * i], act[3 * i + 1], act[3 * i + 2]);
    }

    const float bsum = block_reduce_sum(acc);
    if (threadIdx.x == 0) partial[blockIdx.x] = bsum;
}

__global__ __launch_bounds__(BLOCK) void metric_final_kernel(
        const float* __restrict__ partial, float* __restrict__ out,
        int n, float inv_b) {
    float acc = 0.0f;
    for (int i = threadIdx.x; i < n; i += BLOCK) acc += partial[i];
    const float total = block_reduce_sum(acc);
    if (threadIdx.x == 0) out[0] = total * inv_b;
}

extern "C" void kernel_launch(void* const* d_in, const int* in_sizes, int n_in,
                              void* d_out, int out_size, void* d_ws, size_t ws_size,
                              hipStream_t stream) {
    const float* pred = (const float*)d_in[0];
    const float* act  = (const float*)d_in[1];
    float* out = (float*)d_out;
    float* partial = (float*)d_ws;   // NPART floats = 4 KB scratch

    const int B = in_sizes[0] / 3;

    metric_partial_kernel<<<NPART, BLOCK, 0, stream>>>(pred, act, partial, B);
    metric_final_kernel<<<1, BLOCK, 0, stream>>>(partial, out, NPART, 1.0f / (float)B);
}